// Round 4
// baseline (1626.107 us; speedup 1.0000x reference)
//
#include <hip/hip_runtime.h>
#include <cstddef>
#include <cstdint>

typedef __attribute__((ext_vector_type(4))) float f32x4;
typedef __attribute__((ext_vector_type(8))) short short8;

#define HID 128
#define NK1 -1.4426950408889634f  // -log2(e)
#define PK2 2.8853900817779268f   // +2*log2(e)

// LDS-only barrier: no vmcnt(0) drain.
#define BAR_LGKM() __asm__ volatile("s_waitcnt lgkmcnt(0)\ns_barrier" ::: "memory")
// depth-1 prefetch fence: gather(t) was issued a full timestep ago (~5000 cyc),
// far beyond worst-case HBM latency, so vmcnt(0) here is effectively free.
#define STEP_BAR() __asm__ volatile("s_waitcnt vmcnt(0) lgkmcnt(0)\ns_barrier" ::: "memory")

__device__ __forceinline__ short f2bf(float f) {
  unsigned u = __builtin_bit_cast(unsigned, f);
  u += 0x7FFFu + ((u >> 16) & 1u);
  return (short)(u >> 16);
}
__device__ __forceinline__ unsigned pack_bf2(float a, float b) {
  unsigned ua = __builtin_bit_cast(unsigned, a) + 0x8000u;
  unsigned ub = __builtin_bit_cast(unsigned, b) + 0x8000u;
  return __builtin_amdgcn_perm(ub, ua, 0x07060302u);
}
__device__ __forceinline__ float2 unpack2v(int w) {
  float2 r;
  r.x = __builtin_bit_cast(float, (unsigned)(w << 16));
  r.y = __builtin_bit_cast(float, (unsigned)w & 0xffff0000u);
  return r;
}

// folded LSTM cell: inputs are PRE-SCALED pre-activations
// si,sf,so = -log2e*(gate), sg = 2log2e*(g). 5 exp2 + 2 rcp (algebraic min).
__device__ __forceinline__ float lstm_elem(float si, float sf, float sg, float so, float& c) {
  float Ei = __builtin_amdgcn_exp2f(si);
  float Ef = __builtin_amdgcn_exp2f(sf);
  float Tg = __builtin_amdgcn_exp2f(sg);
  float Eo = __builtin_amdgcn_exp2f(so);
  float u = 1.0f + Ei, w = 1.0f + Ef, v = Tg + 1.0f, Tm = Tg - 1.0f;
  float t0 = u * v;
  float num = __builtin_fmaf(c, t0, w * Tm);
  float cn = num * __builtin_amdgcn_rcpf(w * t0);
  c = cn;
  float Tc = __builtin_amdgcn_exp2f(PK2 * cn);
  return (Tc - 1.0f) * __builtin_amdgcn_rcpf((1.0f + Eo) * (Tc + 1.0f));
}

// ---------------- conversion kernels ----------------
__global__ void conv_x_kernel(const float* __restrict__ x, short* __restrict__ xb, int n,
                              int* __restrict__ tctr) {
  int i = blockIdx.x * blockDim.x + threadIdx.x;
  if (i < 8) tctr[i] = 0;  // zero dynamic-tile counters (runs before all lstm dispatches)
  int stride = gridDim.x * blockDim.x;
  for (; i < n; i += stride) xb[i] = f2bf(x[i]);
}

// pre-scales LSTM weights/bias by gate: i,f,o -> -log2e ; g -> +2log2e
__global__ void conv_layer_kernel(const float* __restrict__ Wih, const float* __restrict__ Whh,
                                  const float* __restrict__ bih, const float* __restrict__ bhh,
                                  const float* __restrict__ Wl, const float* __restrict__ Wr, int foK,
                                  short* __restrict__ wihB, short* __restrict__ whhB,
                                  short* __restrict__ wlB, short* __restrict__ wrB,
                                  float* __restrict__ bsum) {
  int i = blockIdx.x * blockDim.x + threadIdx.x;
  if (i < 512 * HID) {
    float sc = ((i >> 14) == 2) ? PK2 : NK1;  // gate = row>>7 = i>>14
    wihB[i] = f2bf(Wih[i] * sc);
    whhB[i] = f2bf(Whh[i] * sc);
  }
  if (i < foK) { wlB[i] = f2bf(Wl[i]); wrB[i] = f2bf(Wr[i]); }
  if (i < 512) bsum[i] = (bih[i] + bhh[i]) * (((i >> 7) == 2) ? PK2 : NK1);
}

// ------- persistent P-GEMM: P = A @ Wih^T + bias -> bf16 [M,512] -------------
#define OSTR 524
__global__ __launch_bounds__(512, 4) void pgemm_kernel(
    const short* __restrict__ A, const short* __restrict__ W,
    const float* __restrict__ bias, short* __restrict__ out, int M, int ntiles) {
  __shared__ short ldsO[32 * OSTR];  // 33.5 KB
  const int tid = threadIdx.x;
  const int wave = tid >> 6, lane = tid & 63;
  const int quad = lane >> 4, nn = lane & 15;
  const int cbase = wave * 64;

  short8 wreg[4][4];
#pragma unroll
  for (int kt = 0; kt < 4; ++kt)
#pragma unroll
    for (int nt = 0; nt < 4; ++nt)
      wreg[kt][nt] = *(const short8*)(W + (size_t)(cbase + nt * 16 + nn) * HID + kt * 32 + quad * 8);
  f32x4 bias4[4];
#pragma unroll
  for (int nt = 0; nt < 4; ++nt)
#pragma unroll
    for (int r = 0; r < 4; ++r) bias4[nt][r] = bias[cbase + nt * 16 + quad * 4 + r];

#pragma unroll 1
  for (int rt = blockIdx.x; rt < ntiles; rt += gridDim.x) {
    const int row0 = rt * 32;
    f32x4 acc[2][4];
#pragma unroll
    for (int b = 0; b < 2; ++b)
#pragma unroll
      for (int nt = 0; nt < 4; ++nt) acc[b][nt] = bias4[nt];
#pragma unroll
    for (int kt = 0; kt < 4; ++kt) {
      int r0 = row0 + nn;      if (r0 > M - 1) r0 = M - 1;
      int r1 = row0 + 16 + nn; if (r1 > M - 1) r1 = M - 1;
      short8 af0 = *(const short8*)(A + (size_t)r0 * HID + kt * 32 + quad * 8);
      short8 af1 = *(const short8*)(A + (size_t)r1 * HID + kt * 32 + quad * 8);
#pragma unroll
      for (int nt = 0; nt < 4; ++nt) {
        acc[0][nt] = __builtin_amdgcn_mfma_f32_16x16x32_bf16(wreg[kt][nt], af0, acc[0][nt], 0, 0, 0);
        acc[1][nt] = __builtin_amdgcn_mfma_f32_16x16x32_bf16(wreg[kt][nt], af1, acc[1][nt], 0, 0, 0);
      }
    }
    BAR_LGKM();  // previous iteration's ldsO reads complete
#pragma unroll
    for (int b = 0; b < 2; ++b)
#pragma unroll
      for (int nt = 0; nt < 4; ++nt) {
        uint2 pk;
        pk.x = pack_bf2(acc[b][nt][0], acc[b][nt][1]);
        pk.y = pack_bf2(acc[b][nt][2], acc[b][nt][3]);
        *(uint2*)(ldsO + (b * 16 + nn) * OSTR + cbase + nt * 16 + quad * 4) = pk;
      }
    BAR_LGKM();
#pragma unroll
    for (int idx = tid; idx < 32 * 64; idx += 512) {
      int row = idx >> 6, c8 = (idx & 63) * 8;
      if (row0 + row < M)
        *(short8*)(out + (size_t)(row0 + row) * 512 + c8) = *(const short8*)(ldsO + row * OSTR + c8);
    }
  }
}

// ------- persistent LSTM + FUSED output GEMM ---------------------------------
// v5: v0 structure (NPB=16, 2 gather rows/wave) but P double-buffered at
//     prefetch depth 1 (no dummy gathers, vmcnt(0) step fence) -> 44 KB LDS
//     -> THREE blocks/CU = 3 independent recurrence chains per CU.
//     Dynamic tile scheduling + register-resident epilogue weights.
#define NPB 16
#define PSTR 520
#define HSTR 152
#define LSTM_LDS_BYTES ((2 * NPB * PSTR + 2 * NPB * HSTR) * 2 + 256 * 4 + 16)  // 44048

template <int FO, bool RELU, bool OUTF32>
__global__ __launch_bounds__(512, 6) void lstm_fused_kernel(
    const short* __restrict__ P, const short* __restrict__ Whh,
    const int* __restrict__ src, const short* __restrict__ cur,
    const short* __restrict__ Wl, const short* __restrict__ Wr,
    const float* __restrict__ bl,
    short* __restrict__ outB, float* __restrict__ outF, int M, int ntiles,
    int* __restrict__ tctr) {
  extern __shared__ char smem[];
  short* Pb = (short*)smem;                 // [2][16][520]
  short* Hb = Pb + 2 * NPB * PSTR;          // [2][16][152]
  int* srcL = (int*)(Hb + 2 * NPB * HSTR);  // [256]
  int* nextTp = srcL + 256;

  const int tid = threadIdx.x;
  const int wave = tid >> 6, lane = tid & 63;
  const int quad = lane >> 4, nn = lane & 15;
  const int r0row = wave * 2, r1row = wave * 2 + 1;

  // Whh fragments: for each gate q, rows [q*128 + wave*16, +16)  (64 VGPRs)
  short8 wreg[4][4];  // [kt][q]
#pragma unroll
  for (int kt = 0; kt < 4; ++kt)
#pragma unroll
    for (int q = 0; q < 4; ++q)
      wreg[kt][q] = *(const short8*)(Whh + (size_t)(q * 128 + wave * 16 + nn) * HID + kt * 32 + quad * 8);

  // epilogue weights + bias, register-resident (32 VGPRs)
  f32x4 biasO = {0.f, 0.f, 0.f, 0.f};
  short8 wlR[4], wrR[4];
  if (FO == 128 || wave < 4) {
#pragma unroll
    for (int r = 0; r < 4; ++r) biasO[r] = bl[wave * 16 + quad * 4 + r];
#pragma unroll
    for (int kt = 0; kt < 4; ++kt) {
      wlR[kt] = *(const short8*)(Wl + (size_t)(wave * 16 + nn) * HID + kt * 32 + quad * 8);
      wrR[kt] = *(const short8*)(Wr + (size_t)(wave * 16 + nn) * HID + kt * 32 + quad * 8);
    }
  }

  int tile = blockIdx.x;
  while (tile < ntiles) {
    const int nodeBase = tile * NPB;
    if (tid < 256) {
      int node = nodeBase + (tid >> 4);
      srcL[tid] = (node < M) ? src[nodeBase * 16 + tid] : 0;
    }
    if (tid == 0) *nextTp = (int)gridDim.x + atomicAdd(tctr, 1);
    float c_st[4] = {0.f, 0.f, 0.f, 0.f};
    BAR_LGKM();  // srcL + nextT visible; prev tile's LDS reads done
    const int my_next = *nextTp;  // read post-barrier; next write is >16 barriers away

    // prologue: gather(0) -> buf0
    {
      int sa = srcL[r0row * 16 + 0], sb = srcL[r1row * 16 + 0];
      __builtin_amdgcn_global_load_lds(
          (const __attribute__((address_space(1))) unsigned int*)(P + (size_t)sa * 512 + lane * 8),
          (__attribute__((address_space(3))) unsigned int*)(Pb + r0row * PSTR), 16, 0, 0);
      __builtin_amdgcn_global_load_lds(
          (const __attribute__((address_space(1))) unsigned int*)(P + (size_t)sb * 512 + lane * 8),
          (__attribute__((address_space(3))) unsigned int*)(Pb + r1row * PSTR), 16, 0, 0);
    }

#pragma unroll 1
    for (int t = 0; t < 16; ++t) {
      short* Pc = Pb + (t & 1) * NPB * PSTR;          // P(t)
      short* Pg = Pb + ((t + 1) & 1) * NPB * PSTR;    // gather target (t+1)
      const short* Hp = Hb + ((t + 1) & 1) * NPB * HSTR;  // h(t-1)
      short* Hw = Hb + (t & 1) * NPB * HSTR;              // h(t)

      STEP_BAR();  // gather(t) landed (issued one full ts ago); all LDS ops retired

      // ---- read P-frags and unpack INTO acc (MFMA C-operand) ----
      const short* pR = Pc + nn * PSTR + wave * 16 + quad * 4;
      uint2 p0 = *(const uint2*)(pR + 0 * 128);
      uint2 p1 = *(const uint2*)(pR + 1 * 128);
      uint2 p2 = *(const uint2*)(pR + 2 * 128);
      uint2 p3 = *(const uint2*)(pR + 3 * 128);
      f32x4 acc[4];
      {
        float2 u, v;
        u = unpack2v(p0.x); v = unpack2v(p0.y);
        acc[0][0] = u.x; acc[0][1] = u.y; acc[0][2] = v.x; acc[0][3] = v.y;
        u = unpack2v(p1.x); v = unpack2v(p1.y);
        acc[1][0] = u.x; acc[1][1] = u.y; acc[1][2] = v.x; acc[1][3] = v.y;
        u = unpack2v(p2.x); v = unpack2v(p2.y);
        acc[2][0] = u.x; acc[2][1] = u.y; acc[2][2] = v.x; acc[2][3] = v.y;
        u = unpack2v(p3.x); v = unpack2v(p3.y);
        acc[3][0] = u.x; acc[3][1] = u.y; acc[3][2] = v.x; acc[3][3] = v.y;
      }

      // ---- issue gather(t+1) into the other P buffer (no dummies needed) ----
      if (t < 15) {
        int sa = srcL[r0row * 16 + t + 1], sb = srcL[r1row * 16 + t + 1];
        __builtin_amdgcn_global_load_lds(
            (const __attribute__((address_space(1))) unsigned int*)(P + (size_t)sa * 512 + lane * 8),
            (__attribute__((address_space(3))) unsigned int*)(Pg + r0row * PSTR), 16, 0, 0);
        __builtin_amdgcn_global_load_lds(
            (const __attribute__((address_space(1))) unsigned int*)(P + (size_t)sb * 512 + lane * 8),
            (__attribute__((address_space(3))) unsigned int*)(Pg + r1row * PSTR), 16, 0, 0);
      }

      // ---- acc += Whh_rows @ h(t-1)^T ----
      if (t) {
#pragma unroll
        for (int kt = 0; kt < 4; ++kt) {
          short8 hb = *(const short8*)(Hp + nn * HSTR + kt * 32 + quad * 8);
#pragma unroll
          for (int q = 0; q < 4; ++q)
            acc[q] = __builtin_amdgcn_mfma_f32_16x16x32_bf16(wreg[kt][q], hb, acc[q], 0, 0, 0);
        }
      }

      // ---- cell: pure register math, write h(t) ----
      float hv[4];
#pragma unroll
      for (int r = 0; r < 4; ++r)
        hv[r] = lstm_elem(acc[0][r], acc[1][r], acc[2][r], acc[3][r], c_st[r]);
      uint2 pk;
      pk.x = pack_bf2(hv[0], hv[1]);
      pk.y = pack_bf2(hv[2], hv[3]);
      *(uint2*)(Hw + nn * HSTR + wave * 16 + quad * 4) = pk;
    }

    BAR_LGKM();  // h(15) visible (buf1)

    // ---- FUSED output: out[node] = h15@Wl^T + bl + cur@Wr^T ----
    if (FO == 128 || wave < 4) {
      const short* Hf = Hb + NPB * HSTR;
      const int cbase = wave * 16;
      f32x4 accO = biasO;
#pragma unroll
      for (int kt = 0; kt < 4; ++kt) {
        short8 hb = *(const short8*)(Hf + nn * HSTR + kt * 32 + quad * 8);
        accO = __builtin_amdgcn_mfma_f32_16x16x32_bf16(wlR[kt], hb, accO, 0, 0, 0);
        short8 cb = *(const short8*)(cur + (size_t)(nodeBase + nn) * HID + kt * 32 + quad * 8);
        accO = __builtin_amdgcn_mfma_f32_16x16x32_bf16(wrR[kt], cb, accO, 0, 0, 0);
      }
      if (RELU) {
#pragma unroll
        for (int r = 0; r < 4; ++r) accO[r] = fmaxf(accO[r], 0.0f);
      }
      int node = nodeBase + nn;
      if (node < M) {
        if (OUTF32) {
          *(f32x4*)(outF + (size_t)node * FO + cbase + quad * 4) = accO;
        } else {
          uint2 pko;
          pko.x = pack_bf2(accO[0], accO[1]);
          pko.y = pack_bf2(accO[2], accO[3]);
          *(uint2*)(outB + (size_t)node * FO + cbase + quad * 4) = pko;
        }
      }
    }
    tile = my_next;
  }
}

// ---------------- launcher ----------------
extern "C" void kernel_launch(void* const* d_in, const int* in_sizes, int n_in,
                              void* d_out, int out_size, void* d_ws, size_t ws_size,
                              hipStream_t stream) {
  const float* x = (const float*)d_in[0];
  const int* src = (const int*)d_in[1];
  const float* Wih[3] = {(const float*)d_in[2], (const float*)d_in[9], (const float*)d_in[16]};
  const float* Whh[3] = {(const float*)d_in[3], (const float*)d_in[10], (const float*)d_in[17]};
  const float* bih[3] = {(const float*)d_in[4], (const float*)d_in[11], (const float*)d_in[18]};
  const float* bhh[3] = {(const float*)d_in[5], (const float*)d_in[12], (const float*)d_in[19]};
  const float* Wl[3]  = {(const float*)d_in[6], (const float*)d_in[13], (const float*)d_in[20]};
  const float* bl[3]  = {(const float*)d_in[7], (const float*)d_in[14], (const float*)d_in[21]};
  const float* Wr[3]  = {(const float*)d_in[8], (const float*)d_in[15], (const float*)d_in[22]};

  const int M = in_sizes[0] / HID;  // 50000

  char* ws = (char*)d_ws;
  size_t off = 0;
  auto alloc = [&](size_t bytes) -> void* {
    void* p = ws + off;
    off += (bytes + 255) & ~(size_t)255;
    return p;
  };
  short* curA = (short*)alloc((size_t)M * HID * 2);
  short* curB = (short*)alloc((size_t)M * HID * 2);
  short* Pbuf = (short*)alloc((size_t)M * 512 * 2);
  short* wihB[3]; short* whhB[3]; short* wlB[3]; short* wrB[3]; float* bsum[3];
  for (int l = 0; l < 3; ++l) {
    wihB[l] = (short*)alloc(512 * HID * 2);
    whhB[l] = (short*)alloc(512 * HID * 2);
    wlB[l]  = (short*)alloc(HID * HID * 2);
    wrB[l]  = (short*)alloc(HID * HID * 2);
    bsum[l] = (float*)alloc(512 * 4);
  }
  int* tctr = (int*)alloc(256);  // dynamic-tile counters (zeroed by conv_x_kernel)

  const int nltiles = (M + NPB - 1) / NPB;  // 3125
  const int ntiles = (M + 31) / 32;         // 1563

  (void)hipFuncSetAttribute((const void*)lstm_fused_kernel<128, true, false>,
                            hipFuncAttributeMaxDynamicSharedMemorySize, LSTM_LDS_BYTES);
  (void)hipFuncSetAttribute((const void*)lstm_fused_kernel<64, false, true>,
                            hipFuncAttributeMaxDynamicSharedMemorySize, LSTM_LDS_BYTES);

  conv_x_kernel<<<2048, 256, 0, stream>>>(x, curA, M * HID, tctr);
  for (int l = 0; l < 3; ++l) {
    const int Fo = (l == 2) ? 64 : 128;
    conv_layer_kernel<<<256, 256, 0, stream>>>(Wih[l], Whh[l], bih[l], bhh[l], Wl[l], Wr[l],
                                               Fo * HID, wihB[l], whhB[l], wlB[l], wrB[l], bsum[l]);
  }

  short* cur = curA;
  short* nxt = curB;
  for (int l = 0; l < 3; ++l) {
    pgemm_kernel<<<784, 512, 0, stream>>>(cur, wihB[l], bsum[l], Pbuf, M, ntiles);
    if (l < 2) {
      lstm_fused_kernel<128, true, false><<<768, 512, LSTM_LDS_BYTES, stream>>>(
          Pbuf, whhB[l], src, cur, wlB[l], wrB[l], bl[l], nxt, nullptr, M, nltiles, tctr + l);
      short* tswap = cur; cur = nxt; nxt = tswap;
    } else {
      lstm_fused_kernel<64, false, true><<<768, 512, LSTM_LDS_BYTES, stream>>>(
          Pbuf, whhB[l], src, cur, wlB[l], wrB[l], bl[l], nullptr, (float*)d_out, M, nltiles, tctr + 2);
    }
  }
}

// Round 5
// 780.103 us; speedup vs baseline: 2.0845x; 2.0845x over previous
//
#include <hip/hip_runtime.h>
#include <cstddef>
#include <cstdint>

typedef __attribute__((ext_vector_type(4))) float f32x4;
typedef __attribute__((ext_vector_type(8))) short short8;

#define HID 128
#define NK1 -1.4426950408889634f  // -log2(e)
#define PK2 2.8853900817779268f   // +2*log2(e)

// LDS-only barrier: no vmcnt(0) drain.
#define BAR_LGKM() __asm__ volatile("s_waitcnt lgkmcnt(0)\ns_barrier" ::: "memory")
// depth-1 prefetch fence: gather(t) was issued a full timestep ago (~1 interval),
// beyond worst-case HBM latency, so vmcnt(0) here is cheap.
#define STEP_BAR() __asm__ volatile("s_waitcnt vmcnt(0) lgkmcnt(0)\ns_barrier" ::: "memory")

__device__ __forceinline__ short f2bf(float f) {
  unsigned u = __builtin_bit_cast(unsigned, f);
  u += 0x7FFFu + ((u >> 16) & 1u);
  return (short)(u >> 16);
}
__device__ __forceinline__ unsigned pack_bf2(float a, float b) {
  unsigned ua = __builtin_bit_cast(unsigned, a) + 0x8000u;
  unsigned ub = __builtin_bit_cast(unsigned, b) + 0x8000u;
  return __builtin_amdgcn_perm(ub, ua, 0x07060302u);
}
__device__ __forceinline__ float2 unpack2v(int w) {
  float2 r;
  r.x = __builtin_bit_cast(float, (unsigned)(w << 16));
  r.y = __builtin_bit_cast(float, (unsigned)w & 0xffff0000u);
  return r;
}

// folded LSTM cell: inputs are PRE-SCALED pre-activations
// si,sf,so = -log2e*(gate), sg = 2log2e*(g). 5 exp2 + 2 rcp (algebraic min).
__device__ __forceinline__ float lstm_elem(float si, float sf, float sg, float so, float& c) {
  float Ei = __builtin_amdgcn_exp2f(si);
  float Ef = __builtin_amdgcn_exp2f(sf);
  float Tg = __builtin_amdgcn_exp2f(sg);
  float Eo = __builtin_amdgcn_exp2f(so);
  float u = 1.0f + Ei, w = 1.0f + Ef, v = Tg + 1.0f, Tm = Tg - 1.0f;
  float t0 = u * v;
  float num = __builtin_fmaf(c, t0, w * Tm);
  float cn = num * __builtin_amdgcn_rcpf(w * t0);
  c = cn;
  float Tc = __builtin_amdgcn_exp2f(PK2 * cn);
  return (Tc - 1.0f) * __builtin_amdgcn_rcpf((1.0f + Eo) * (Tc + 1.0f));
}

// ---------------- conversion kernels ----------------
__global__ void conv_x_kernel(const float* __restrict__ x, short* __restrict__ xb, int n,
                              int* __restrict__ tctr) {
  int i = blockIdx.x * blockDim.x + threadIdx.x;
  if (i < 8) tctr[i] = 0;  // zero dynamic-tile counters (runs before all lstm dispatches)
  int stride = gridDim.x * blockDim.x;
  for (; i < n; i += stride) xb[i] = f2bf(x[i]);
}

// pre-scales LSTM weights/bias by gate: i,f,o -> -log2e ; g -> +2log2e
__global__ void conv_layer_kernel(const float* __restrict__ Wih, const float* __restrict__ Whh,
                                  const float* __restrict__ bih, const float* __restrict__ bhh,
                                  const float* __restrict__ Wl, const float* __restrict__ Wr, int foK,
                                  short* __restrict__ wihB, short* __restrict__ whhB,
                                  short* __restrict__ wlB, short* __restrict__ wrB,
                                  float* __restrict__ bsum) {
  int i = blockIdx.x * blockDim.x + threadIdx.x;
  if (i < 512 * HID) {
    float sc = ((i >> 14) == 2) ? PK2 : NK1;  // gate = row>>7 = i>>14
    wihB[i] = f2bf(Wih[i] * sc);
    whhB[i] = f2bf(Whh[i] * sc);
  }
  if (i < foK) { wlB[i] = f2bf(Wl[i]); wrB[i] = f2bf(Wr[i]); }
  if (i < 512) bsum[i] = (bih[i] + bhh[i]) * (((i >> 7) == 2) ? PK2 : NK1);
}

// ------- persistent P-GEMM: P = A @ Wih^T + bias -> bf16 [M,512] -------------
#define OSTR 524
__global__ __launch_bounds__(512, 4) void pgemm_kernel(
    const short* __restrict__ A, const short* __restrict__ W,
    const float* __restrict__ bias, short* __restrict__ out, int M, int ntiles) {
  __shared__ short ldsO[32 * OSTR];  // 33.5 KB
  const int tid = threadIdx.x;
  const int wave = tid >> 6, lane = tid & 63;
  const int quad = lane >> 4, nn = lane & 15;
  const int cbase = wave * 64;

  short8 wreg[4][4];
#pragma unroll
  for (int kt = 0; kt < 4; ++kt)
#pragma unroll
    for (int nt = 0; nt < 4; ++nt)
      wreg[kt][nt] = *(const short8*)(W + (size_t)(cbase + nt * 16 + nn) * HID + kt * 32 + quad * 8);
  f32x4 bias4[4];
#pragma unroll
  for (int nt = 0; nt < 4; ++nt)
#pragma unroll
    for (int r = 0; r < 4; ++r) bias4[nt][r] = bias[cbase + nt * 16 + quad * 4 + r];

#pragma unroll 1
  for (int rt = blockIdx.x; rt < ntiles; rt += gridDim.x) {
    const int row0 = rt * 32;
    f32x4 acc[2][4];
#pragma unroll
    for (int b = 0; b < 2; ++b)
#pragma unroll
      for (int nt = 0; nt < 4; ++nt) acc[b][nt] = bias4[nt];
#pragma unroll
    for (int kt = 0; kt < 4; ++kt) {
      int r0 = row0 + nn;      if (r0 > M - 1) r0 = M - 1;
      int r1 = row0 + 16 + nn; if (r1 > M - 1) r1 = M - 1;
      short8 af0 = *(const short8*)(A + (size_t)r0 * HID + kt * 32 + quad * 8);
      short8 af1 = *(const short8*)(A + (size_t)r1 * HID + kt * 32 + quad * 8);
#pragma unroll
      for (int nt = 0; nt < 4; ++nt) {
        acc[0][nt] = __builtin_amdgcn_mfma_f32_16x16x32_bf16(wreg[kt][nt], af0, acc[0][nt], 0, 0, 0);
        acc[1][nt] = __builtin_amdgcn_mfma_f32_16x16x32_bf16(wreg[kt][nt], af1, acc[1][nt], 0, 0, 0);
      }
    }
    BAR_LGKM();  // previous iteration's ldsO reads complete
#pragma unroll
    for (int b = 0; b < 2; ++b)
#pragma unroll
      for (int nt = 0; nt < 4; ++nt) {
        uint2 pk;
        pk.x = pack_bf2(acc[b][nt][0], acc[b][nt][1]);
        pk.y = pack_bf2(acc[b][nt][2], acc[b][nt][3]);
        *(uint2*)(ldsO + (b * 16 + nn) * OSTR + cbase + nt * 16 + quad * 4) = pk;
      }
    BAR_LGKM();
#pragma unroll
    for (int idx = tid; idx < 32 * 64; idx += 512) {
      int row = idx >> 6, c8 = (idx & 63) * 8;
      if (row0 + row < M)
        *(short8*)(out + (size_t)(row0 + row) * 512 + c8) = *(const short8*)(ldsO + row * OSTR + c8);
    }
  }
}

// ------- persistent LSTM + FUSED output GEMM ---------------------------------
// v6: v5 structure (NPB=16, P double-buffered, depth-1 prefetch, 44 KB LDS
//     -> 3 blocks/CU via the LDS limit) but launch_bounds back to (512,4):
//     v5's (512,6) capped the allocator at ~85 VGPR -> 40 VGPR + scratch
//     spills of wreg/wlR/wrR (FETCH 4x, WRITE 10x). (512,4) compiles at
//     64 VGPR (rounds 0-2), which allows 8 waves/SIMD -- occupancy is then
//     LDS-limited at 3 blocks/CU, no allocator pressure.
#define NPB 16
#define PSTR 520
#define HSTR 152
#define LSTM_LDS_BYTES ((2 * NPB * PSTR + 2 * NPB * HSTR) * 2 + 256 * 4 + 16)  // 44048

template <int FO, bool RELU, bool OUTF32>
__global__ __launch_bounds__(512, 4) void lstm_fused_kernel(
    const short* __restrict__ P, const short* __restrict__ Whh,
    const int* __restrict__ src, const short* __restrict__ cur,
    const short* __restrict__ Wl, const short* __restrict__ Wr,
    const float* __restrict__ bl,
    short* __restrict__ outB, float* __restrict__ outF, int M, int ntiles,
    int* __restrict__ tctr) {
  extern __shared__ char smem[];
  short* Pb = (short*)smem;                 // [2][16][520]
  short* Hb = Pb + 2 * NPB * PSTR;          // [2][16][152]
  int* srcL = (int*)(Hb + 2 * NPB * HSTR);  // [256]
  int* nextTp = srcL + 256;

  const int tid = threadIdx.x;
  const int wave = tid >> 6, lane = tid & 63;
  const int quad = lane >> 4, nn = lane & 15;
  const int r0row = wave * 2, r1row = wave * 2 + 1;

  // Whh fragments: for each gate q, rows [q*128 + wave*16, +16)  (64 VGPRs)
  short8 wreg[4][4];  // [kt][q]
#pragma unroll
  for (int kt = 0; kt < 4; ++kt)
#pragma unroll
    for (int q = 0; q < 4; ++q)
      wreg[kt][q] = *(const short8*)(Whh + (size_t)(q * 128 + wave * 16 + nn) * HID + kt * 32 + quad * 8);

  // epilogue weights + bias, register-resident (32 VGPRs)
  f32x4 biasO = {0.f, 0.f, 0.f, 0.f};
  short8 wlR[4], wrR[4];
  if (FO == 128 || wave < 4) {
#pragma unroll
    for (int r = 0; r < 4; ++r) biasO[r] = bl[wave * 16 + quad * 4 + r];
#pragma unroll
    for (int kt = 0; kt < 4; ++kt) {
      wlR[kt] = *(const short8*)(Wl + (size_t)(wave * 16 + nn) * HID + kt * 32 + quad * 8);
      wrR[kt] = *(const short8*)(Wr + (size_t)(wave * 16 + nn) * HID + kt * 32 + quad * 8);
    }
  }

  int tile = blockIdx.x;
  while (tile < ntiles) {
    const int nodeBase = tile * NPB;
    if (tid < 256) {
      int node = nodeBase + (tid >> 4);
      srcL[tid] = (node < M) ? src[nodeBase * 16 + tid] : 0;
    }
    if (tid == 0) *nextTp = (int)gridDim.x + atomicAdd(tctr, 1);
    float c_st[4] = {0.f, 0.f, 0.f, 0.f};
    BAR_LGKM();  // srcL + nextT visible; prev tile's LDS reads done
    const int my_next = *nextTp;  // read post-barrier; next write is >16 barriers away

    // prologue: gather(0) -> buf0
    {
      int sa = srcL[r0row * 16 + 0], sb = srcL[r1row * 16 + 0];
      __builtin_amdgcn_global_load_lds(
          (const __attribute__((address_space(1))) unsigned int*)(P + (size_t)sa * 512 + lane * 8),
          (__attribute__((address_space(3))) unsigned int*)(Pb + r0row * PSTR), 16, 0, 0);
      __builtin_amdgcn_global_load_lds(
          (const __attribute__((address_space(1))) unsigned int*)(P + (size_t)sb * 512 + lane * 8),
          (__attribute__((address_space(3))) unsigned int*)(Pb + r1row * PSTR), 16, 0, 0);
    }

#pragma unroll 1
    for (int t = 0; t < 16; ++t) {
      short* Pc = Pb + (t & 1) * NPB * PSTR;          // P(t)
      short* Pg = Pb + ((t + 1) & 1) * NPB * PSTR;    // gather target (t+1)
      const short* Hp = Hb + ((t + 1) & 1) * NPB * HSTR;  // h(t-1)
      short* Hw = Hb + (t & 1) * NPB * HSTR;              // h(t)

      STEP_BAR();  // gather(t) landed (issued one full ts ago); all LDS ops retired

      // ---- read P-frags and unpack INTO acc (MFMA C-operand) ----
      const short* pR = Pc + nn * PSTR + wave * 16 + quad * 4;
      uint2 p0 = *(const uint2*)(pR + 0 * 128);
      uint2 p1 = *(const uint2*)(pR + 1 * 128);
      uint2 p2 = *(const uint2*)(pR + 2 * 128);
      uint2 p3 = *(const uint2*)(pR + 3 * 128);
      f32x4 acc[4];
      {
        float2 u, v;
        u = unpack2v(p0.x); v = unpack2v(p0.y);
        acc[0][0] = u.x; acc[0][1] = u.y; acc[0][2] = v.x; acc[0][3] = v.y;
        u = unpack2v(p1.x); v = unpack2v(p1.y);
        acc[1][0] = u.x; acc[1][1] = u.y; acc[1][2] = v.x; acc[1][3] = v.y;
        u = unpack2v(p2.x); v = unpack2v(p2.y);
        acc[2][0] = u.x; acc[2][1] = u.y; acc[2][2] = v.x; acc[2][3] = v.y;
        u = unpack2v(p3.x); v = unpack2v(p3.y);
        acc[3][0] = u.x; acc[3][1] = u.y; acc[3][2] = v.x; acc[3][3] = v.y;
      }

      // ---- issue gather(t+1) into the other P buffer (no dummies needed) ----
      if (t < 15) {
        int sa = srcL[r0row * 16 + t + 1], sb = srcL[r1row * 16 + t + 1];
        __builtin_amdgcn_global_load_lds(
            (const __attribute__((address_space(1))) unsigned int*)(P + (size_t)sa * 512 + lane * 8),
            (__attribute__((address_space(3))) unsigned int*)(Pg + r0row * PSTR), 16, 0, 0);
        __builtin_amdgcn_global_load_lds(
            (const __attribute__((address_space(1))) unsigned int*)(P + (size_t)sb * 512 + lane * 8),
            (__attribute__((address_space(3))) unsigned int*)(Pg + r1row * PSTR), 16, 0, 0);
      }

      // ---- acc += Whh_rows @ h(t-1)^T ----
      if (t) {
#pragma unroll
        for (int kt = 0; kt < 4; ++kt) {
          short8 hb = *(const short8*)(Hp + nn * HSTR + kt * 32 + quad * 8);
#pragma unroll
          for (int q = 0; q < 4; ++q)
            acc[q] = __builtin_amdgcn_mfma_f32_16x16x32_bf16(wreg[kt][q], hb, acc[q], 0, 0, 0);
        }
      }

      // ---- cell: pure register math, write h(t) ----
      float hv[4];
#pragma unroll
      for (int r = 0; r < 4; ++r)
        hv[r] = lstm_elem(acc[0][r], acc[1][r], acc[2][r], acc[3][r], c_st[r]);
      uint2 pk;
      pk.x = pack_bf2(hv[0], hv[1]);
      pk.y = pack_bf2(hv[2], hv[3]);
      *(uint2*)(Hw + nn * HSTR + wave * 16 + quad * 4) = pk;
    }

    BAR_LGKM();  // h(15) visible (buf1)

    // ---- FUSED output: out[node] = h15@Wl^T + bl + cur@Wr^T ----
    if (FO == 128 || wave < 4) {
      const short* Hf = Hb + NPB * HSTR;
      const int cbase = wave * 16;
      f32x4 accO = biasO;
#pragma unroll
      for (int kt = 0; kt < 4; ++kt) {
        short8 hb = *(const short8*)(Hf + nn * HSTR + kt * 32 + quad * 8);
        accO = __builtin_amdgcn_mfma_f32_16x16x32_bf16(wlR[kt], hb, accO, 0, 0, 0);
        short8 cb = *(const short8*)(cur + (size_t)(nodeBase + nn) * HID + kt * 32 + quad * 8);
        accO = __builtin_amdgcn_mfma_f32_16x16x32_bf16(wrR[kt], cb, accO, 0, 0, 0);
      }
      if (RELU) {
#pragma unroll
        for (int r = 0; r < 4; ++r) accO[r] = fmaxf(accO[r], 0.0f);
      }
      int node = nodeBase + nn;
      if (node < M) {
        if (OUTF32) {
          *(f32x4*)(outF + (size_t)node * FO + cbase + quad * 4) = accO;
        } else {
          uint2 pko;
          pko.x = pack_bf2(accO[0], accO[1]);
          pko.y = pack_bf2(accO[2], accO[3]);
          *(uint2*)(outB + (size_t)node * FO + cbase + quad * 4) = pko;
        }
      }
    }
    tile = my_next;
  }
}

// ---------------- launcher ----------------
extern "C" void kernel_launch(void* const* d_in, const int* in_sizes, int n_in,
                              void* d_out, int out_size, void* d_ws, size_t ws_size,
                              hipStream_t stream) {
  const float* x = (const float*)d_in[0];
  const int* src = (const int*)d_in[1];
  const float* Wih[3] = {(const float*)d_in[2], (const float*)d_in[9], (const float*)d_in[16]};
  const float* Whh[3] = {(const float*)d_in[3], (const float*)d_in[10], (const float*)d_in[17]};
  const float* bih[3] = {(const float*)d_in[4], (const float*)d_in[11], (const float*)d_in[18]};
  const float* bhh[3] = {(const float*)d_in[5], (const float*)d_in[12], (const float*)d_in[19]};
  const float* Wl[3]  = {(const float*)d_in[6], (const float*)d_in[13], (const float*)d_in[20]};
  const float* bl[3]  = {(const float*)d_in[7], (const float*)d_in[14], (const float*)d_in[21]};
  const float* Wr[3]  = {(const float*)d_in[8], (const float*)d_in[15], (const float*)d_in[22]};

  const int M = in_sizes[0] / HID;  // 50000

  char* ws = (char*)d_ws;
  size_t off = 0;
  auto alloc = [&](size_t bytes) -> void* {
    void* p = ws + off;
    off += (bytes + 255) & ~(size_t)255;
    return p;
  };
  short* curA = (short*)alloc((size_t)M * HID * 2);
  short* curB = (short*)alloc((size_t)M * HID * 2);
  short* Pbuf = (short*)alloc((size_t)M * 512 * 2);
  short* wihB[3]; short* whhB[3]; short* wlB[3]; short* wrB[3]; float* bsum[3];
  for (int l = 0; l < 3; ++l) {
    wihB[l] = (short*)alloc(512 * HID * 2);
    whhB[l] = (short*)alloc(512 * HID * 2);
    wlB[l]  = (short*)alloc(HID * HID * 2);
    wrB[l]  = (short*)alloc(HID * HID * 2);
    bsum[l] = (float*)alloc(512 * 4);
  }
  int* tctr = (int*)alloc(256);  // dynamic-tile counters (zeroed by conv_x_kernel)

  const int nltiles = (M + NPB - 1) / NPB;  // 3125
  const int ntiles = (M + 31) / 32;         // 1563

  (void)hipFuncSetAttribute((const void*)lstm_fused_kernel<128, true, false>,
                            hipFuncAttributeMaxDynamicSharedMemorySize, LSTM_LDS_BYTES);
  (void)hipFuncSetAttribute((const void*)lstm_fused_kernel<64, false, true>,
                            hipFuncAttributeMaxDynamicSharedMemorySize, LSTM_LDS_BYTES);

  conv_x_kernel<<<2048, 256, 0, stream>>>(x, curA, M * HID, tctr);
  for (int l = 0; l < 3; ++l) {
    const int Fo = (l == 2) ? 64 : 128;
    conv_layer_kernel<<<256, 256, 0, stream>>>(Wih[l], Whh[l], bih[l], bhh[l], Wl[l], Wr[l],
                                               Fo * HID, wihB[l], whhB[l], wlB[l], wrB[l], bsum[l]);
  }

  short* cur = curA;
  short* nxt = curB;
  for (int l = 0; l < 3; ++l) {
    pgemm_kernel<<<784, 512, 0, stream>>>(cur, wihB[l], bsum[l], Pbuf, M, ntiles);
    if (l < 2) {
      lstm_fused_kernel<128, true, false><<<768, 512, LSTM_LDS_BYTES, stream>>>(
          Pbuf, whhB[l], src, cur, wlB[l], wrB[l], bl[l], nxt, nullptr, M, nltiles, tctr + l);
      short* tswap = cur; cur = nxt; nxt = tswap;
    } else {
      lstm_fused_kernel<64, false, true><<<768, 512, LSTM_LDS_BYTES, stream>>>(
          Pbuf, whhB[l], src, cur, wlB[l], wrB[l], bl[l], nullptr, (float*)d_out, M, nltiles, tctr + 2);
    }
  }
}

// Round 6
// 736.532 us; speedup vs baseline: 2.2078x; 1.0592x over previous
//
#include <hip/hip_runtime.h>
#include <cstddef>
#include <cstdint>

typedef __attribute__((ext_vector_type(4))) float f32x4;
typedef __attribute__((ext_vector_type(8))) short short8;

#define HID 128
#define NK1 -1.4426950408889634f  // -log2(e)
#define PK2 2.8853900817779268f   // +2*log2(e)

// LDS-only barrier: no vmcnt(0) drain.
#define BAR_LGKM() __asm__ volatile("s_waitcnt lgkmcnt(0)\ns_barrier" ::: "memory")
// depth-2 prefetch fence: retire gather(t), keep gather(t+1) in flight
#define STEP_BAR2() __asm__ volatile("s_waitcnt vmcnt(2) lgkmcnt(0)\ns_barrier" ::: "memory")

__device__ __forceinline__ short f2bf(float f) {
  unsigned u = __builtin_bit_cast(unsigned, f);
  u += 0x7FFFu + ((u >> 16) & 1u);
  return (short)(u >> 16);
}
__device__ __forceinline__ unsigned pack_bf2(float a, float b) {
  unsigned ua = __builtin_bit_cast(unsigned, a) + 0x8000u;
  unsigned ub = __builtin_bit_cast(unsigned, b) + 0x8000u;
  return __builtin_amdgcn_perm(ub, ua, 0x07060302u);
}
__device__ __forceinline__ float2 unpack2v(int w) {
  float2 r;
  r.x = __builtin_bit_cast(float, (unsigned)(w << 16));
  r.y = __builtin_bit_cast(float, (unsigned)w & 0xffff0000u);
  return r;
}

// folded LSTM cell: inputs are PRE-SCALED pre-activations
// si,sf,so = -log2e*(gate), sg = 2log2e*(g). 5 exp2 + 2 rcp (algebraic min).
__device__ __forceinline__ float lstm_elem(float si, float sf, float sg, float so, float& c) {
  float Ei = __builtin_amdgcn_exp2f(si);
  float Ef = __builtin_amdgcn_exp2f(sf);
  float Tg = __builtin_amdgcn_exp2f(sg);
  float Eo = __builtin_amdgcn_exp2f(so);
  float u = 1.0f + Ei, w = 1.0f + Ef, v = Tg + 1.0f, Tm = Tg - 1.0f;
  float t0 = u * v;
  float num = __builtin_fmaf(c, t0, w * Tm);
  float cn = num * __builtin_amdgcn_rcpf(w * t0);
  c = cn;
  float Tc = __builtin_amdgcn_exp2f(PK2 * cn);
  return (Tc - 1.0f) * __builtin_amdgcn_rcpf((1.0f + Eo) * (Tc + 1.0f));
}

// ---------------- conversion kernels ----------------
__global__ void conv_x_kernel(const float* __restrict__ x, short* __restrict__ xb, int n,
                              int* __restrict__ tctr) {
  int i = blockIdx.x * blockDim.x + threadIdx.x;
  if (i < 8) tctr[i] = 0;  // zero dynamic-tile counters (runs before all lstm dispatches)
  int stride = gridDim.x * blockDim.x;
  for (; i < n; i += stride) xb[i] = f2bf(x[i]);
}

// pre-scales LSTM weights/bias by gate: i,f,o -> -log2e ; g -> +2log2e
__global__ void conv_layer_kernel(const float* __restrict__ Wih, const float* __restrict__ Whh,
                                  const float* __restrict__ bih, const float* __restrict__ bhh,
                                  const float* __restrict__ Wl, const float* __restrict__ Wr, int foK,
                                  short* __restrict__ wihB, short* __restrict__ whhB,
                                  short* __restrict__ wlB, short* __restrict__ wrB,
                                  float* __restrict__ bsum) {
  int i = blockIdx.x * blockDim.x + threadIdx.x;
  if (i < 512 * HID) {
    float sc = ((i >> 14) == 2) ? PK2 : NK1;  // gate = row>>7 = i>>14
    wihB[i] = f2bf(Wih[i] * sc);
    whhB[i] = f2bf(Whh[i] * sc);
  }
  if (i < foK) { wlB[i] = f2bf(Wl[i]); wrB[i] = f2bf(Wr[i]); }
  if (i < 512) bsum[i] = (bih[i] + bhh[i]) * (((i >> 7) == 2) ? PK2 : NK1);
}

// ------- persistent P-GEMM: P = A @ Wih^T + bias -> bf16 [M,512] -------------
#define OSTR 524
__global__ __launch_bounds__(512, 4) void pgemm_kernel(
    const short* __restrict__ A, const short* __restrict__ W,
    const float* __restrict__ bias, short* __restrict__ out, int M, int ntiles) {
  __shared__ short ldsO[32 * OSTR];  // 33.5 KB
  const int tid = threadIdx.x;
  const int wave = tid >> 6, lane = tid & 63;
  const int quad = lane >> 4, nn = lane & 15;
  const int cbase = wave * 64;

  short8 wreg[4][4];
#pragma unroll
  for (int kt = 0; kt < 4; ++kt)
#pragma unroll
    for (int nt = 0; nt < 4; ++nt)
      wreg[kt][nt] = *(const short8*)(W + (size_t)(cbase + nt * 16 + nn) * HID + kt * 32 + quad * 8);
  f32x4 bias4[4];
#pragma unroll
  for (int nt = 0; nt < 4; ++nt)
#pragma unroll
    for (int r = 0; r < 4; ++r) bias4[nt][r] = bias[cbase + nt * 16 + quad * 4 + r];

#pragma unroll 1
  for (int rt = blockIdx.x; rt < ntiles; rt += gridDim.x) {
    const int row0 = rt * 32;
    f32x4 acc[2][4];
#pragma unroll
    for (int b = 0; b < 2; ++b)
#pragma unroll
      for (int nt = 0; nt < 4; ++nt) acc[b][nt] = bias4[nt];
#pragma unroll
    for (int kt = 0; kt < 4; ++kt) {
      int r0 = row0 + nn;      if (r0 > M - 1) r0 = M - 1;
      int r1 = row0 + 16 + nn; if (r1 > M - 1) r1 = M - 1;
      short8 af0 = *(const short8*)(A + (size_t)r0 * HID + kt * 32 + quad * 8);
      short8 af1 = *(const short8*)(A + (size_t)r1 * HID + kt * 32 + quad * 8);
#pragma unroll
      for (int nt = 0; nt < 4; ++nt) {
        acc[0][nt] = __builtin_amdgcn_mfma_f32_16x16x32_bf16(wreg[kt][nt], af0, acc[0][nt], 0, 0, 0);
        acc[1][nt] = __builtin_amdgcn_mfma_f32_16x16x32_bf16(wreg[kt][nt], af1, acc[1][nt], 0, 0, 0);
      }
    }
    BAR_LGKM();  // previous iteration's ldsO reads complete
#pragma unroll
    for (int b = 0; b < 2; ++b)
#pragma unroll
      for (int nt = 0; nt < 4; ++nt) {
        uint2 pk;
        pk.x = pack_bf2(acc[b][nt][0], acc[b][nt][1]);
        pk.y = pack_bf2(acc[b][nt][2], acc[b][nt][3]);
        *(uint2*)(ldsO + (b * 16 + nn) * OSTR + cbase + nt * 16 + quad * 4) = pk;
      }
    BAR_LGKM();
#pragma unroll
    for (int idx = tid; idx < 32 * 64; idx += 512) {
      int row = idx >> 6, c8 = (idx & 63) * 8;
      if (row0 + row < M)
        *(short8*)(out + (size_t)(row0 + row) * 512 + c8) = *(const short8*)(ldsO + row * OSTR + c8);
    }
  }
}

// ------- persistent LSTM + FUSED output GEMM ---------------------------------
// v7: round-0 pipeline (NPB=16, 3 P-buffers, vmcnt(2) fence — best measured)
//     + dynamic tile scheduling, MINUS the epilogue register residency:
//     wlR/wrR/biasO (−36 regs) are re-loaded from global once per tile.
//     Theory: total VGPR+AGPR ~170 has pinned every round at 3 waves/SIMD;
//     dropping to ~128 crosses the quantization boundary to 4 waves/SIMD
//     (2 full blocks/CU resident).
#define NPB 16
#define PSTR 520
#define HSTR 152
#define LSTM_LDS_BYTES ((3 * NPB * PSTR + 2 * NPB * HSTR) * 2 + 256 * 4 + 16)  // 60688

template <int FO, bool RELU, bool OUTF32>
__global__ __launch_bounds__(512, 4) void lstm_fused_kernel(
    const short* __restrict__ P, const short* __restrict__ Whh,
    const int* __restrict__ src, const short* __restrict__ cur,
    const short* __restrict__ Wl, const short* __restrict__ Wr,
    const float* __restrict__ bl,
    short* __restrict__ outB, float* __restrict__ outF, int M, int ntiles,
    int* __restrict__ tctr) {
  extern __shared__ char smem[];
  short* Pb = (short*)smem;                 // [3][16][520]
  short* Hb = Pb + 3 * NPB * PSTR;          // [2][16][152]
  int* srcL = (int*)(Hb + 2 * NPB * HSTR);  // [256]
  int* nextTp = srcL + 256;

  const int tid = threadIdx.x;
  const int wave = tid >> 6, lane = tid & 63;
  const int quad = lane >> 4, nn = lane & 15;
  const int r0row = wave * 2, r1row = wave * 2 + 1;

  // Whh fragments: for each gate q, rows [q*128 + wave*16, +16)  (64 VGPRs)
  short8 wreg[4][4];  // [kt][q]
#pragma unroll
  for (int kt = 0; kt < 4; ++kt)
#pragma unroll
    for (int q = 0; q < 4; ++q)
      wreg[kt][q] = *(const short8*)(Whh + (size_t)(q * 128 + wave * 16 + nn) * HID + kt * 32 + quad * 8);

  int tile = blockIdx.x;
  while (tile < ntiles) {
    const int nodeBase = tile * NPB;
    if (tid < 256) {
      int node = nodeBase + (tid >> 4);
      srcL[tid] = (node < M) ? src[nodeBase * 16 + tid] : 0;
    }
    if (tid == 0) *nextTp = (int)gridDim.x + atomicAdd(tctr, 1);
    float c_st[4] = {0.f, 0.f, 0.f, 0.f};
    BAR_LGKM();  // srcL + nextT visible; prev tile's LDS reads done
    const int my_next = *nextTp;  // read post-barrier; next write is >16 barriers away

    // prologue: gather(0) -> buf0, gather(1) -> buf1
    {
      int s0A = srcL[r0row * 16 + 0], s0B = srcL[r1row * 16 + 0];
      __builtin_amdgcn_global_load_lds(
          (const __attribute__((address_space(1))) unsigned int*)(P + (size_t)s0A * 512 + lane * 8),
          (__attribute__((address_space(3))) unsigned int*)(Pb + r0row * PSTR), 16, 0, 0);
      __builtin_amdgcn_global_load_lds(
          (const __attribute__((address_space(1))) unsigned int*)(P + (size_t)s0B * 512 + lane * 8),
          (__attribute__((address_space(3))) unsigned int*)(Pb + r1row * PSTR), 16, 0, 0);
      int s1A = srcL[r0row * 16 + 1], s1B = srcL[r1row * 16 + 1];
      __builtin_amdgcn_global_load_lds(
          (const __attribute__((address_space(1))) unsigned int*)(P + (size_t)s1A * 512 + lane * 8),
          (__attribute__((address_space(3))) unsigned int*)(Pb + NPB * PSTR + r0row * PSTR), 16, 0, 0);
      __builtin_amdgcn_global_load_lds(
          (const __attribute__((address_space(1))) unsigned int*)(P + (size_t)s1B * 512 + lane * 8),
          (__attribute__((address_space(3))) unsigned int*)(Pb + NPB * PSTR + r1row * PSTR), 16, 0, 0);
    }
    int sA = srcL[r0row * 16 + 2], sB = srcL[r1row * 16 + 2];

    int pc = 0, pg = 2;  // buffer index of P(t) and of gather target (t+2)
#pragma unroll 1
    for (int t = 0; t < 16; ++t) {
      short* Pc = Pb + pc * NPB * PSTR;
      short* Pg = Pb + pg * NPB * PSTR;
      const short* Hp = Hb + ((t + 1) & 1) * NPB * HSTR;  // h(t-1)
      short* Hw = Hb + (t & 1) * NPB * HSTR;              // h(t)
      pc = (pc == 2) ? 0 : pc + 1;
      pg = (pg == 2) ? 0 : pg + 1;

      STEP_BAR2();  // gather(t) landed everywhere; gather(t+1) stays in flight

      // ---- read P-frags and unpack INTO acc (MFMA C-operand) ----
      const short* pR = Pc + nn * PSTR + wave * 16 + quad * 4;
      uint2 p0 = *(const uint2*)(pR + 0 * 128);
      uint2 p1 = *(const uint2*)(pR + 1 * 128);
      uint2 p2 = *(const uint2*)(pR + 2 * 128);
      uint2 p3 = *(const uint2*)(pR + 3 * 128);
      f32x4 acc[4];
      {
        float2 u, v;
        u = unpack2v(p0.x); v = unpack2v(p0.y);
        acc[0][0] = u.x; acc[0][1] = u.y; acc[0][2] = v.x; acc[0][3] = v.y;
        u = unpack2v(p1.x); v = unpack2v(p1.y);
        acc[1][0] = u.x; acc[1][1] = u.y; acc[1][2] = v.x; acc[1][3] = v.y;
        u = unpack2v(p2.x); v = unpack2v(p2.y);
        acc[2][0] = u.x; acc[2][1] = u.y; acc[2][2] = v.x; acc[2][3] = v.y;
        u = unpack2v(p3.x); v = unpack2v(p3.y);
        acc[3][0] = u.x; acc[3][1] = u.y; acc[3][2] = v.x; acc[3][3] = v.y;
      }

      // ---- issue gather(t+2) (clamped dummy at t>=14 keeps vmcnt uniform) ----
      __builtin_amdgcn_global_load_lds(
          (const __attribute__((address_space(1))) unsigned int*)(P + (size_t)sA * 512 + lane * 8),
          (__attribute__((address_space(3))) unsigned int*)(Pg + r0row * PSTR), 16, 0, 0);
      __builtin_amdgcn_global_load_lds(
          (const __attribute__((address_space(1))) unsigned int*)(P + (size_t)sB * 512 + lane * 8),
          (__attribute__((address_space(3))) unsigned int*)(Pg + r1row * PSTR), 16, 0, 0);
      {
        int tn = (t + 3 < 16) ? t + 3 : 15;
        sA = srcL[r0row * 16 + tn];
        sB = srcL[r1row * 16 + tn];
      }

      // ---- acc += Whh_rows @ h(t-1)^T ----
      if (t) {
#pragma unroll
        for (int kt = 0; kt < 4; ++kt) {
          short8 hb = *(const short8*)(Hp + nn * HSTR + kt * 32 + quad * 8);
#pragma unroll
          for (int q = 0; q < 4; ++q)
            acc[q] = __builtin_amdgcn_mfma_f32_16x16x32_bf16(wreg[kt][q], hb, acc[q], 0, 0, 0);
        }
      }

      // ---- cell: pure register math, write h(t) ----
      float hv[4];
#pragma unroll
      for (int r = 0; r < 4; ++r)
        hv[r] = lstm_elem(acc[0][r], acc[1][r], acc[2][r], acc[3][r], c_st[r]);
      uint2 pk;
      pk.x = pack_bf2(hv[0], hv[1]);
      pk.y = pack_bf2(hv[2], hv[3]);
      *(uint2*)(Hw + nn * HSTR + wave * 16 + quad * 4) = pk;
    }

    BAR_LGKM();  // h(15) visible (buf1)

    // ---- FUSED output: out[node] = h15@Wl^T + bl + cur@Wr^T ----
    // weights/bias loaded from global HERE (once per tile) to keep them out of
    // the persistent register budget (the occupancy hypothesis of this round).
    if (FO == 128 || wave < 4) {
      const short* Hf = Hb + NPB * HSTR;
      const int cbase = wave * 16;
      f32x4 accO;
#pragma unroll
      for (int r = 0; r < 4; ++r) accO[r] = bl[cbase + quad * 4 + r];
#pragma unroll
      for (int kt = 0; kt < 4; ++kt) {
        short8 wlA = *(const short8*)(Wl + (size_t)(cbase + nn) * HID + kt * 32 + quad * 8);
        short8 hb = *(const short8*)(Hf + nn * HSTR + kt * 32 + quad * 8);
        accO = __builtin_amdgcn_mfma_f32_16x16x32_bf16(wlA, hb, accO, 0, 0, 0);
        short8 wrA = *(const short8*)(Wr + (size_t)(cbase + nn) * HID + kt * 32 + quad * 8);
        short8 cb = *(const short8*)(cur + (size_t)(nodeBase + nn) * HID + kt * 32 + quad * 8);
        accO = __builtin_amdgcn_mfma_f32_16x16x32_bf16(wrA, cb, accO, 0, 0, 0);
      }
      if (RELU) {
#pragma unroll
        for (int r = 0; r < 4; ++r) accO[r] = fmaxf(accO[r], 0.0f);
      }
      int node = nodeBase + nn;
      if (node < M) {
        if (OUTF32) {
          *(f32x4*)(outF + (size_t)node * FO + cbase + quad * 4) = accO;
        } else {
          uint2 pko;
          pko.x = pack_bf2(accO[0], accO[1]);
          pko.y = pack_bf2(accO[2], accO[3]);
          *(uint2*)(outB + (size_t)node * FO + cbase + quad * 4) = pko;
        }
      }
    }
    tile = my_next;
  }
}

// ---------------- launcher ----------------
extern "C" void kernel_launch(void* const* d_in, const int* in_sizes, int n_in,
                              void* d_out, int out_size, void* d_ws, size_t ws_size,
                              hipStream_t stream) {
  const float* x = (const float*)d_in[0];
  const int* src = (const int*)d_in[1];
  const float* Wih[3] = {(const float*)d_in[2], (const float*)d_in[9], (const float*)d_in[16]};
  const float* Whh[3] = {(const float*)d_in[3], (const float*)d_in[10], (const float*)d_in[17]};
  const float* bih[3] = {(const float*)d_in[4], (const float*)d_in[11], (const float*)d_in[18]};
  const float* bhh[3] = {(const float*)d_in[5], (const float*)d_in[12], (const float*)d_in[19]};
  const float* Wl[3]  = {(const float*)d_in[6], (const float*)d_in[13], (const float*)d_in[20]};
  const float* bl[3]  = {(const float*)d_in[7], (const float*)d_in[14], (const float*)d_in[21]};
  const float* Wr[3]  = {(const float*)d_in[8], (const float*)d_in[15], (const float*)d_in[22]};

  const int M = in_sizes[0] / HID;  // 50000

  char* ws = (char*)d_ws;
  size_t off = 0;
  auto alloc = [&](size_t bytes) -> void* {
    void* p = ws + off;
    off += (bytes + 255) & ~(size_t)255;
    return p;
  };
  short* curA = (short*)alloc((size_t)M * HID * 2);
  short* curB = (short*)alloc((size_t)M * HID * 2);
  short* Pbuf = (short*)alloc((size_t)M * 512 * 2);
  short* wihB[3]; short* whhB[3]; short* wlB[3]; short* wrB[3]; float* bsum[3];
  for (int l = 0; l < 3; ++l) {
    wihB[l] = (short*)alloc(512 * HID * 2);
    whhB[l] = (short*)alloc(512 * HID * 2);
    wlB[l]  = (short*)alloc(HID * HID * 2);
    wrB[l]  = (short*)alloc(HID * HID * 2);
    bsum[l] = (float*)alloc(512 * 4);
  }
  int* tctr = (int*)alloc(256);  // dynamic-tile counters (zeroed by conv_x_kernel)

  const int nltiles = (M + NPB - 1) / NPB;  // 3125
  const int ntiles = (M + 31) / 32;         // 1563

  (void)hipFuncSetAttribute((const void*)lstm_fused_kernel<128, true, false>,
                            hipFuncAttributeMaxDynamicSharedMemorySize, LSTM_LDS_BYTES);
  (void)hipFuncSetAttribute((const void*)lstm_fused_kernel<64, false, true>,
                            hipFuncAttributeMaxDynamicSharedMemorySize, LSTM_LDS_BYTES);

  conv_x_kernel<<<2048, 256, 0, stream>>>(x, curA, M * HID, tctr);
  for (int l = 0; l < 3; ++l) {
    const int Fo = (l == 2) ? 64 : 128;
    conv_layer_kernel<<<256, 256, 0, stream>>>(Wih[l], Whh[l], bih[l], bhh[l], Wl[l], Wr[l],
                                               Fo * HID, wihB[l], whhB[l], wlB[l], wrB[l], bsum[l]);
  }

  short* cur = curA;
  short* nxt = curB;
  for (int l = 0; l < 3; ++l) {
    pgemm_kernel<<<784, 512, 0, stream>>>(cur, wihB[l], bsum[l], Pbuf, M, ntiles);
    if (l < 2) {
      lstm_fused_kernel<128, true, false><<<512, 512, LSTM_LDS_BYTES, stream>>>(
          Pbuf, whhB[l], src, cur, wlB[l], wrB[l], bl[l], nxt, nullptr, M, nltiles, tctr + l);
      short* tswap = cur; cur = nxt; nxt = tswap;
    } else {
      lstm_fused_kernel<64, false, true><<<512, 512, LSTM_LDS_BYTES, stream>>>(
          Pbuf, whhB[l], src, cur, wlB[l], wrB[l], bl[l], nullptr, (float*)d_out, M, nltiles, tctr + 2);
    }
  }
}

// Round 7
// 700.305 us; speedup vs baseline: 2.3220x; 1.0517x over previous
//
#include <hip/hip_runtime.h>
#include <cstddef>
#include <cstdint>

typedef __attribute__((ext_vector_type(4))) float f32x4;
typedef __attribute__((ext_vector_type(8))) short short8;

#define HID 128
#define NK1 -1.4426950408889634f  // -log2(e)
#define PK2 2.8853900817779268f   // +2*log2(e)

// LDS-only barrier: no vmcnt(0) drain.
#define BAR_LGKM() __asm__ volatile("s_waitcnt lgkmcnt(0)\ns_barrier" ::: "memory")
// depth-2 prefetch fence: retire gather(t), keep gather(t+1) in flight
#define STEP_BAR2() __asm__ volatile("s_waitcnt vmcnt(2) lgkmcnt(0)\ns_barrier" ::: "memory")
// staging fence: A-tile DMA/ds_write visible to all waves
#define BAR_VM_LGKM() __asm__ volatile("s_waitcnt vmcnt(0) lgkmcnt(0)\ns_barrier" ::: "memory")

__device__ __forceinline__ short f2bf(float f) {
  unsigned u = __builtin_bit_cast(unsigned, f);
  u += 0x7FFFu + ((u >> 16) & 1u);
  return (short)(u >> 16);
}
__device__ __forceinline__ unsigned pack_bf2(float a, float b) {
  unsigned ua = __builtin_bit_cast(unsigned, a) + 0x8000u;
  unsigned ub = __builtin_bit_cast(unsigned, b) + 0x8000u;
  return __builtin_amdgcn_perm(ub, ua, 0x07060302u);
}
__device__ __forceinline__ float2 unpack2v(int w) {
  float2 r;
  r.x = __builtin_bit_cast(float, (unsigned)(w << 16));
  r.y = __builtin_bit_cast(float, (unsigned)w & 0xffff0000u);
  return r;
}

// folded LSTM cell: inputs are PRE-SCALED pre-activations
// si,sf,so = -log2e*(gate), sg = 2log2e*(g). 5 exp2 + 2 rcp (algebraic min).
__device__ __forceinline__ float lstm_elem(float si, float sf, float sg, float so, float& c) {
  float Ei = __builtin_amdgcn_exp2f(si);
  float Ef = __builtin_amdgcn_exp2f(sf);
  float Tg = __builtin_amdgcn_exp2f(sg);
  float Eo = __builtin_amdgcn_exp2f(so);
  float u = 1.0f + Ei, w = 1.0f + Ef, v = Tg + 1.0f, Tm = Tg - 1.0f;
  float t0 = u * v;
  float num = __builtin_fmaf(c, t0, w * Tm);
  float cn = num * __builtin_amdgcn_rcpf(w * t0);
  c = cn;
  float Tc = __builtin_amdgcn_exp2f(PK2 * cn);
  return (Tc - 1.0f) * __builtin_amdgcn_rcpf((1.0f + Eo) * (Tc + 1.0f));
}

// ---------------- conversion kernels ----------------
__global__ void conv_x_kernel(const float* __restrict__ x, short* __restrict__ xb, int n,
                              int* __restrict__ tctr) {
  int i = blockIdx.x * blockDim.x + threadIdx.x;
  if (i < 8) tctr[i] = 0;  // zero dynamic-tile counters (runs before all lstm dispatches)
  int stride = gridDim.x * blockDim.x;
  for (; i < n; i += stride) xb[i] = f2bf(x[i]);
}

// pre-scales LSTM weights/bias by gate: i,f,o -> -log2e ; g -> +2log2e
__global__ void conv_layer_kernel(const float* __restrict__ Wih, const float* __restrict__ Whh,
                                  const float* __restrict__ bih, const float* __restrict__ bhh,
                                  const float* __restrict__ Wl, const float* __restrict__ Wr, int foK,
                                  short* __restrict__ wihB, short* __restrict__ whhB,
                                  short* __restrict__ wlB, short* __restrict__ wrB,
                                  float* __restrict__ bsum) {
  int i = blockIdx.x * blockDim.x + threadIdx.x;
  if (i < 512 * HID) {
    float sc = ((i >> 14) == 2) ? PK2 : NK1;  // gate = row>>7 = i>>14
    wihB[i] = f2bf(Wih[i] * sc);
    whhB[i] = f2bf(Whh[i] * sc);
  }
  if (i < foK) { wlB[i] = f2bf(Wl[i]); wrB[i] = f2bf(Wr[i]); }
  if (i < 512) bsum[i] = (bih[i] + bhh[i]) * (((i >> 7) == 2) ? PK2 : NK1);
}

// ------- persistent P-GEMM: P = A @ Wih^T + bias -> bf16 [M,512] -------------
// v2: A-tile staged in LDS once per tile (was: all 8 waves issuing IDENTICAL
//     global loads per kt — 8x redundant VMEM). Each wave loads 4 distinct
//     rows to registers (1 dwordx4/lane) and ds_writes into a padded [32][136]
//     tile (pad breaks the 256B-stride bank collision a linear tile would
//     have; reg-staging because the pad forbids global_load_lds).
#define OSTR 524
#define ASTR 136
__global__ __launch_bounds__(512, 4) void pgemm_kernel(
    const short* __restrict__ A, const short* __restrict__ W,
    const float* __restrict__ bias, short* __restrict__ out, int M, int ntiles) {
  __shared__ short ldsA[32 * ASTR];  // 8.5 KB
  __shared__ short ldsO[32 * OSTR];  // 33.5 KB
  const int tid = threadIdx.x;
  const int wave = tid >> 6, lane = tid & 63;
  const int quad = lane >> 4, nn = lane & 15;
  const int cbase = wave * 64;

  short8 wreg[4][4];
#pragma unroll
  for (int kt = 0; kt < 4; ++kt)
#pragma unroll
    for (int nt = 0; nt < 4; ++nt)
      wreg[kt][nt] = *(const short8*)(W + (size_t)(cbase + nt * 16 + nn) * HID + kt * 32 + quad * 8);
  f32x4 bias4[4];
#pragma unroll
  for (int nt = 0; nt < 4; ++nt)
#pragma unroll
    for (int r = 0; r < 4; ++r) bias4[nt][r] = bias[cbase + nt * 16 + quad * 4 + r];

  // staging indices: this wave stages rows [wave*4, +4), lane covers row
  // wave*4 + (lane>>4), cols (lane&15)*8 .. +8
  const int srow = wave * 4 + quad;
  const int scol = nn * 8;

#pragma unroll 1
  for (int rt = blockIdx.x; rt < ntiles; rt += gridDim.x) {
    const int row0 = rt * 32;
    // ---- stage A tile: 1 global dwordx4 + 1 ds_write_b128 per lane ----
    {
      int r = row0 + srow;
      if (r > M - 1) r = M - 1;
      short8 av = *(const short8*)(A + (size_t)r * HID + scol);
      *(short8*)(ldsA + srow * ASTR + scol) = av;
    }
    BAR_VM_LGKM();  // A tile visible to all waves

    f32x4 acc[2][4];
#pragma unroll
    for (int b = 0; b < 2; ++b)
#pragma unroll
      for (int nt = 0; nt < 4; ++nt) acc[b][nt] = bias4[nt];
#pragma unroll
    for (int kt = 0; kt < 4; ++kt) {
      short8 af0 = *(const short8*)(ldsA + nn * ASTR + kt * 32 + quad * 8);
      short8 af1 = *(const short8*)(ldsA + (16 + nn) * ASTR + kt * 32 + quad * 8);
#pragma unroll
      for (int nt = 0; nt < 4; ++nt) {
        acc[0][nt] = __builtin_amdgcn_mfma_f32_16x16x32_bf16(wreg[kt][nt], af0, acc[0][nt], 0, 0, 0);
        acc[1][nt] = __builtin_amdgcn_mfma_f32_16x16x32_bf16(wreg[kt][nt], af1, acc[1][nt], 0, 0, 0);
      }
    }
    BAR_LGKM();  // ldsA reads + previous iteration's ldsO reads complete
#pragma unroll
    for (int b = 0; b < 2; ++b)
#pragma unroll
      for (int nt = 0; nt < 4; ++nt) {
        uint2 pk;
        pk.x = pack_bf2(acc[b][nt][0], acc[b][nt][1]);
        pk.y = pack_bf2(acc[b][nt][2], acc[b][nt][3]);
        *(uint2*)(ldsO + (b * 16 + nn) * OSTR + cbase + nt * 16 + quad * 4) = pk;
      }
    BAR_LGKM();
#pragma unroll
    for (int idx = tid; idx < 32 * 64; idx += 512) {
      int row = idx >> 6, c8 = (idx & 63) * 8;
      if (row0 + row < M)
        *(short8*)(out + (size_t)(row0 + row) * 512 + c8) = *(const short8*)(ldsO + row * OSTR + c8);
    }
  }
}

// ------- persistent LSTM + FUSED output GEMM ---------------------------------
// v8: identical to v7/R6 (best measured: 195 us) except srcL holds pre-shifted
//     BYTE offsets (s*1024) — one less shl per gather issue.
#define NPB 16
#define PSTR 520
#define HSTR 152
#define LSTM_LDS_BYTES ((3 * NPB * PSTR + 2 * NPB * HSTR) * 2 + 256 * 4 + 16)  // 60688

template <int FO, bool RELU, bool OUTF32>
__global__ __launch_bounds__(512, 4) void lstm_fused_kernel(
    const short* __restrict__ P, const short* __restrict__ Whh,
    const int* __restrict__ src, const short* __restrict__ cur,
    const short* __restrict__ Wl, const short* __restrict__ Wr,
    const float* __restrict__ bl,
    short* __restrict__ outB, float* __restrict__ outF, int M, int ntiles,
    int* __restrict__ tctr) {
  extern __shared__ char smem[];
  short* Pb = (short*)smem;                 // [3][16][520]
  short* Hb = Pb + 3 * NPB * PSTR;          // [2][16][152]
  int* srcL = (int*)(Hb + 2 * NPB * HSTR);  // [256] byte offsets into P
  int* nextTp = srcL + 256;

  const int tid = threadIdx.x;
  const int wave = tid >> 6, lane = tid & 63;
  const int quad = lane >> 4, nn = lane & 15;
  const int r0row = wave * 2, r1row = wave * 2 + 1;
  const char* Pbase = (const char*)P + lane * 16;  // per-lane 16B column base

  // Whh fragments: for each gate q, rows [q*128 + wave*16, +16)  (64 VGPRs)
  short8 wreg[4][4];  // [kt][q]
#pragma unroll
  for (int kt = 0; kt < 4; ++kt)
#pragma unroll
    for (int q = 0; q < 4; ++q)
      wreg[kt][q] = *(const short8*)(Whh + (size_t)(q * 128 + wave * 16 + nn) * HID + kt * 32 + quad * 8);

  int tile = blockIdx.x;
  while (tile < ntiles) {
    const int nodeBase = tile * NPB;
    if (tid < 256) {
      int node = nodeBase + (tid >> 4);
      srcL[tid] = ((node < M) ? src[nodeBase * 16 + tid] : 0) << 10;  // byte offset (row*1024)
    }
    if (tid == 0) *nextTp = (int)gridDim.x + atomicAdd(tctr, 1);
    float c_st[4] = {0.f, 0.f, 0.f, 0.f};
    BAR_LGKM();  // srcL + nextT visible; prev tile's LDS reads done
    const int my_next = *nextTp;  // read post-barrier; next write is >16 barriers away

    // prologue: gather(0) -> buf0, gather(1) -> buf1
    {
      int s0A = srcL[r0row * 16 + 0], s0B = srcL[r1row * 16 + 0];
      __builtin_amdgcn_global_load_lds(
          (const __attribute__((address_space(1))) unsigned int*)(Pbase + s0A),
          (__attribute__((address_space(3))) unsigned int*)(Pb + r0row * PSTR), 16, 0, 0);
      __builtin_amdgcn_global_load_lds(
          (const __attribute__((address_space(1))) unsigned int*)(Pbase + s0B),
          (__attribute__((address_space(3))) unsigned int*)(Pb + r1row * PSTR), 16, 0, 0);
      int s1A = srcL[r0row * 16 + 1], s1B = srcL[r1row * 16 + 1];
      __builtin_amdgcn_global_load_lds(
          (const __attribute__((address_space(1))) unsigned int*)(Pbase + s1A),
          (__attribute__((address_space(3))) unsigned int*)(Pb + NPB * PSTR + r0row * PSTR), 16, 0, 0);
      __builtin_amdgcn_global_load_lds(
          (const __attribute__((address_space(1))) unsigned int*)(Pbase + s1B),
          (__attribute__((address_space(3))) unsigned int*)(Pb + NPB * PSTR + r1row * PSTR), 16, 0, 0);
    }
    int sA = srcL[r0row * 16 + 2], sB = srcL[r1row * 16 + 2];

    int pc = 0, pg = 2;  // buffer index of P(t) and of gather target (t+2)
#pragma unroll 1
    for (int t = 0; t < 16; ++t) {
      short* Pc = Pb + pc * NPB * PSTR;
      short* Pg = Pb + pg * NPB * PSTR;
      const short* Hp = Hb + ((t + 1) & 1) * NPB * HSTR;  // h(t-1)
      short* Hw = Hb + (t & 1) * NPB * HSTR;              // h(t)
      pc = (pc == 2) ? 0 : pc + 1;
      pg = (pg == 2) ? 0 : pg + 1;

      STEP_BAR2();  // gather(t) landed everywhere; gather(t+1) stays in flight

      // ---- read P-frags and unpack INTO acc (MFMA C-operand) ----
      const short* pR = Pc + nn * PSTR + wave * 16 + quad * 4;
      uint2 p0 = *(const uint2*)(pR + 0 * 128);
      uint2 p1 = *(const uint2*)(pR + 1 * 128);
      uint2 p2 = *(const uint2*)(pR + 2 * 128);
      uint2 p3 = *(const uint2*)(pR + 3 * 128);
      f32x4 acc[4];
      {
        float2 u, v;
        u = unpack2v(p0.x); v = unpack2v(p0.y);
        acc[0][0] = u.x; acc[0][1] = u.y; acc[0][2] = v.x; acc[0][3] = v.y;
        u = unpack2v(p1.x); v = unpack2v(p1.y);
        acc[1][0] = u.x; acc[1][1] = u.y; acc[1][2] = v.x; acc[1][3] = v.y;
        u = unpack2v(p2.x); v = unpack2v(p2.y);
        acc[2][0] = u.x; acc[2][1] = u.y; acc[2][2] = v.x; acc[2][3] = v.y;
        u = unpack2v(p3.x); v = unpack2v(p3.y);
        acc[3][0] = u.x; acc[3][1] = u.y; acc[3][2] = v.x; acc[3][3] = v.y;
      }

      // ---- issue gather(t+2) (clamped dummy at t>=14 keeps vmcnt uniform) ----
      __builtin_amdgcn_global_load_lds(
          (const __attribute__((address_space(1))) unsigned int*)(Pbase + sA),
          (__attribute__((address_space(3))) unsigned int*)(Pg + r0row * PSTR), 16, 0, 0);
      __builtin_amdgcn_global_load_lds(
          (const __attribute__((address_space(1))) unsigned int*)(Pbase + sB),
          (__attribute__((address_space(3))) unsigned int*)(Pg + r1row * PSTR), 16, 0, 0);
      {
        int tn = (t + 3 < 16) ? t + 3 : 15;
        sA = srcL[r0row * 16 + tn];
        sB = srcL[r1row * 16 + tn];
      }

      // ---- acc += Whh_rows @ h(t-1)^T ----
      if (t) {
#pragma unroll
        for (int kt = 0; kt < 4; ++kt) {
          short8 hb = *(const short8*)(Hp + nn * HSTR + kt * 32 + quad * 8);
#pragma unroll
          for (int q = 0; q < 4; ++q)
            acc[q] = __builtin_amdgcn_mfma_f32_16x16x32_bf16(wreg[kt][q], hb, acc[q], 0, 0, 0);
        }
      }

      // ---- cell: pure register math, write h(t) ----
      float hv[4];
#pragma unroll
      for (int r = 0; r < 4; ++r)
        hv[r] = lstm_elem(acc[0][r], acc[1][r], acc[2][r], acc[3][r], c_st[r]);
      uint2 pk;
      pk.x = pack_bf2(hv[0], hv[1]);
      pk.y = pack_bf2(hv[2], hv[3]);
      *(uint2*)(Hw + nn * HSTR + wave * 16 + quad * 4) = pk;
    }

    BAR_LGKM();  // h(15) visible (buf1)

    // ---- FUSED output: out[node] = h15@Wl^T + bl + cur@Wr^T ----
    // weights/bias loaded from global HERE (once per tile) to stay out of the
    // persistent register budget (occupancy: 2 blocks/CU at ~128 regs).
    if (FO == 128 || wave < 4) {
      const short* Hf = Hb + NPB * HSTR;
      const int cbase = wave * 16;
      f32x4 accO;
#pragma unroll
      for (int r = 0; r < 4; ++r) accO[r] = bl[cbase + quad * 4 + r];
#pragma unroll
      for (int kt = 0; kt < 4; ++kt) {
        short8 wlA = *(const short8*)(Wl + (size_t)(cbase + nn) * HID + kt * 32 + quad * 8);
        short8 hb = *(const short8*)(Hf + nn * HSTR + kt * 32 + quad * 8);
        accO = __builtin_amdgcn_mfma_f32_16x16x32_bf16(wlA, hb, accO, 0, 0, 0);
        short8 wrA = *(const short8*)(Wr + (size_t)(cbase + nn) * HID + kt * 32 + quad * 8);
        short8 cb = *(const short8*)(cur + (size_t)(nodeBase + nn) * HID + kt * 32 + quad * 8);
        accO = __builtin_amdgcn_mfma_f32_16x16x32_bf16(wrA, cb, accO, 0, 0, 0);
      }
      if (RELU) {
#pragma unroll
        for (int r = 0; r < 4; ++r) accO[r] = fmaxf(accO[r], 0.0f);
      }
      int node = nodeBase + nn;
      if (node < M) {
        if (OUTF32) {
          *(f32x4*)(outF + (size_t)node * FO + cbase + quad * 4) = accO;
        } else {
          uint2 pko;
          pko.x = pack_bf2(accO[0], accO[1]);
          pko.y = pack_bf2(accO[2], accO[3]);
          *(uint2*)(outB + (size_t)node * FO + cbase + quad * 4) = pko;
        }
      }
    }
    tile = my_next;
  }
}

// ---------------- launcher ----------------
extern "C" void kernel_launch(void* const* d_in, const int* in_sizes, int n_in,
                              void* d_out, int out_size, void* d_ws, size_t ws_size,
                              hipStream_t stream) {
  const float* x = (const float*)d_in[0];
  const int* src = (const int*)d_in[1];
  const float* Wih[3] = {(const float*)d_in[2], (const float*)d_in[9], (const float*)d_in[16]};
  const float* Whh[3] = {(const float*)d_in[3], (const float*)d_in[10], (const float*)d_in[17]};
  const float* bih[3] = {(const float*)d_in[4], (const float*)d_in[11], (const float*)d_in[18]};
  const float* bhh[3] = {(const float*)d_in[5], (const float*)d_in[12], (const float*)d_in[19]};
  const float* Wl[3]  = {(const float*)d_in[6], (const float*)d_in[13], (const float*)d_in[20]};
  const float* bl[3]  = {(const float*)d_in[7], (const float*)d_in[14], (const float*)d_in[21]};
  const float* Wr[3]  = {(const float*)d_in[8], (const float*)d_in[15], (const float*)d_in[22]};

  const int M = in_sizes[0] / HID;  // 50000

  char* ws = (char*)d_ws;
  size_t off = 0;
  auto alloc = [&](size_t bytes) -> void* {
    void* p = ws + off;
    off += (bytes + 255) & ~(size_t)255;
    return p;
  };
  short* curA = (short*)alloc((size_t)M * HID * 2);
  short* curB = (short*)alloc((size_t)M * HID * 2);
  short* Pbuf = (short*)alloc((size_t)M * 512 * 2);
  short* wihB[3]; short* whhB[3]; short* wlB[3]; short* wrB[3]; float* bsum[3];
  for (int l = 0; l < 3; ++l) {
    wihB[l] = (short*)alloc(512 * HID * 2);
    whhB[l] = (short*)alloc(512 * HID * 2);
    wlB[l]  = (short*)alloc(HID * HID * 2);
    wrB[l]  = (short*)alloc(HID * HID * 2);
    bsum[l] = (float*)alloc(512 * 4);
  }
  int* tctr = (int*)alloc(256);  // dynamic-tile counters (zeroed by conv_x_kernel)

  const int nltiles = (M + NPB - 1) / NPB;  // 3125
  const int ntiles = (M + 31) / 32;         // 1563

  (void)hipFuncSetAttribute((const void*)lstm_fused_kernel<128, true, false>,
                            hipFuncAttributeMaxDynamicSharedMemorySize, LSTM_LDS_BYTES);
  (void)hipFuncSetAttribute((const void*)lstm_fused_kernel<64, false, true>,
                            hipFuncAttributeMaxDynamicSharedMemorySize, LSTM_LDS_BYTES);

  conv_x_kernel<<<2048, 256, 0, stream>>>(x, curA, M * HID, tctr);
  for (int l = 0; l < 3; ++l) {
    const int Fo = (l == 2) ? 64 : 128;
    conv_layer_kernel<<<256, 256, 0, stream>>>(Wih[l], Whh[l], bih[l], bhh[l], Wl[l], Wr[l],
                                               Fo * HID, wihB[l], whhB[l], wlB[l], wrB[l], bsum[l]);
  }

  short* cur = curA;
  short* nxt = curB;
  for (int l = 0; l < 3; ++l) {
    pgemm_kernel<<<784, 512, 0, stream>>>(cur, wihB[l], bsum[l], Pbuf, M, ntiles);
    if (l < 2) {
      lstm_fused_kernel<128, true, false><<<512, 512, LSTM_LDS_BYTES, stream>>>(
          Pbuf, whhB[l], src, cur, wlB[l], wrB[l], bl[l], nxt, nullptr, M, nltiles, tctr + l);
      short* tswap = cur; cur = nxt; nxt = tswap;
    } else {
      lstm_fused_kernel<64, false, true><<<512, 512, LSTM_LDS_BYTES, stream>>>(
          Pbuf, whhB[l], src, cur, wlB[l], wrB[l], bl[l], nullptr, (float*)d_out, M, nltiles, tctr + 2);
    }
  }
}